// Round 3
// baseline (336.148 us; speedup 1.0000x reference)
//
#include <hip/hip_runtime.h>
#include <stdint.h>

#define WDIM 128
#define HID 256
#define G3 768
#define BATCH 4096
#define SEQ 32
#define BM 16
#define THREADS 512

// ws layout (ushort units): WiT[768][128], WhT[768][256], WpT[256][256], gx[131072][768]
#define WS_WIT 0
#define WS_WHT 98304
#define WS_WPT 294912
#define WS_WTOTAL 360448
#define WS_GX  362496ULL               // byte offset 724992 (4KB aligned)
#define WS_NEEDED (724992ULL + 201326592ULL)

typedef __attribute__((ext_vector_type(8))) short short8;
typedef __attribute__((ext_vector_type(4))) float f32x4;

#define MFMA(a, b, c) __builtin_amdgcn_mfma_f32_16x16x32_bf16((a), (b), (c), 0, 0, 0)

__device__ __forceinline__ ushort f2bf(float f) {
    union { float f; uint32_t u; } v; v.f = f;
    uint32_t u = v.u;
    u += 0x7fffu + ((u >> 16) & 1u);   // RNE
    return (ushort)(u >> 16);
}
__device__ __forceinline__ float bf2f(uint32_t b) {
    union { uint32_t u; float f; } v; v.u = b << 16; return v.f;
}
__device__ __forceinline__ float sigmoidf_(float x) {
    return __builtin_amdgcn_rcpf(1.f + __expf(-x));
}
__device__ __forceinline__ float tanhf_(float x) {
    float e2 = __expf(2.f * x);
    return 1.f - 2.f * __builtin_amdgcn_rcpf(e2 + 1.f);
}

__global__ void prep_kernel(const float* __restrict__ wi, const float* __restrict__ wh,
                            const float* __restrict__ wp, ushort* __restrict__ ws) {
    int gid = blockIdx.x * blockDim.x + threadIdx.x;
    if (gid < G3 * WDIM) {
        int n = gid / WDIM, k = gid % WDIM;
        ws[WS_WIT + n * WDIM + k] = f2bf(wi[k * G3 + n]);
    } else if (gid < G3 * WDIM + G3 * HID) {
        int g = gid - G3 * WDIM;
        int n = g / HID, k = g % HID;
        ws[WS_WHT + n * HID + k] = f2bf(wh[k * G3 + n]);
    } else if (gid < G3 * WDIM + G3 * HID + HID * HID) {
        int g = gid - G3 * WDIM - G3 * HID;
        int n = g / HID, k = g % HID;
        ws[WS_WPT + n * HID + k] = f2bf(wp[k * HID + n]);
    }
}

// ============ gx = bf16( embed[x] @ Wi + b ) : M=131072, N=768, K=128 ============
#define GXM 64
#define GXN 128

__global__ __launch_bounds__(256, 4) void gx_kernel(
    const int* __restrict__ x, const float* __restrict__ embed,
    const float* __restrict__ bias, const ushort* __restrict__ WiT,
    ushort* __restrict__ gx)
{
    __shared__ char At[16384];           // [64 rows][256B] bf16, XOR-swizzled
    const int tid  = threadIdx.x;
    const int lane = tid & 63, wid = tid >> 6;
    const int lrow = lane & 15, kgrp = lane >> 4;
    const int m0  = blockIdx.x * GXM;
    const int nc0 = blockIdx.y * GXN;

    {   // gather 64 embedding rows -> LDS bf16 (4 threads/row, 32 floats each)
        int row = tid >> 2, part = tid & 3;
        int tok = x[m0 + row];
        const float* e = embed + (size_t)tok * WDIM + part * 32;
        #pragma unroll
        for (int q = 0; q < 8; ++q) {
            float4 f = ((const float4*)e)[q];
            uint32_t p0 = f2bf(f.x) | ((uint32_t)f2bf(f.y) << 16);
            uint32_t p1 = f2bf(f.z) | ((uint32_t)f2bf(f.w) << 16);
            *(uint2*)(At + row * 256 + ((part * 64 + q * 8) ^ ((row & 7) << 4))) = (uint2){p0, p1};
        }
    }
    __syncthreads();

    f32x4 acc[8];
    #pragma unroll
    for (int n = 0; n < 8; ++n) acc[n] = (f32x4){0,0,0,0};

    const int arow = wid * 16 + lrow;
    #pragma unroll
    for (int ks = 0; ks < 4; ++ks) {
        short8 a = *(const short8*)(At + arow * 256 + ((ks * 64 + kgrp * 16) ^ ((arow & 7) << 4)));
        #pragma unroll
        for (int n = 0; n < 8; ++n) {
            int col = nc0 + n * 16 + lrow;
            short8 b = *(const short8*)&WiT[(size_t)col * WDIM + ks * 32 + kgrp * 8];
            acc[n] = MFMA(a, b, acc[n]);
        }
    }
    #pragma unroll
    for (int n = 0; n < 8; ++n) {
        int col = nc0 + n * 16 + lrow;
        float bv = bias[col];
        #pragma unroll
        for (int j = 0; j < 4; ++j) {
            size_t m = (size_t)(m0 + wid * 16 + kgrp * 4 + j);
            gx[m * G3 + col] = f2bf(acc[n][j] + bv);
        }
    }
}

// ============ recurrent kernel: h-part only, gx prefetched ============
#define R_WHA 0          // Wh_a swizzled [256 cols][512B]  (128KB)
#define R_HBF 131072     // [16][512B] bf16 h, swizzled
#define R_RH  139264     // [16][512B] bf16 r*h, swizzled
#define R_TOTAL 147456

extern __shared__ char smem[];

__global__ __launch_bounds__(THREADS, 2) void gru_rec(
    const ushort* __restrict__ gx, const float* __restrict__ bp,
    const ushort* __restrict__ WhT, const ushort* __restrict__ WpT,
    float* __restrict__ out)
{
    char* WhA = smem + R_WHA;
    char* HBF = smem + R_HBF;
    char* RH  = smem + R_RH;

    const int tid  = threadIdx.x;
    const int lane = tid & 63;
    const int wid  = tid >> 6;
    const int lrow = lane & 15;
    const int kgrp = lane >> 4;
    const int r0   = blockIdx.x * BM;
    const int ncol0 = wid * 32;

    // one-time LDS fill: Wh_a swizzled
    for (int c = tid; c < 8192; c += THREADS) {
        int row = c >> 5, ch = c & 31;
        short8 v = *(const short8*)&WhT[(size_t)(2 * HID + row) * HID + ch * 8];
        *(short8*)(WhA + row * 512 + ((ch * 16) ^ ((row & 7) << 4))) = v;
    }
    *(short8*)(HBF + tid * 16) = (short8){0,0,0,0,0,0,0,0};

    // resident Wh z/r fragments (128 VGPR), pinned against rematerialization
    short8 Wz[8][2], Wr[8][2];
    #pragma unroll
    for (int ks = 0; ks < 8; ++ks)
        #pragma unroll
        for (int n = 0; n < 2; ++n) {
            int colg = ncol0 + n * 16 + lrow;
            Wz[ks][n] = *(const short8*)&WhT[(size_t)colg * HID + ks * 32 + kgrp * 8];
            Wr[ks][n] = *(const short8*)&WhT[(size_t)(HID + colg) * HID + ks * 32 + kgrp * 8];
            asm volatile("" : "+v"(Wz[ks][n]), "+v"(Wr[ks][n]));
        }

    float bpr[2];
    #pragma unroll
    for (int n = 0; n < 2; ++n) bpr[n] = bp[ncol0 + n * 16 + lrow];

    float h[2][4] = {{0.f,0.f,0.f,0.f},{0.f,0.f,0.f,0.f}};

    // gx base pointers per j (row = kgrp*4+j), col base ncol0+lrow, t=0
    const ushort* gbase[4];
    #pragma unroll
    for (int j = 0; j < 4; ++j)
        gbase[j] = gx + ((size_t)(r0 + kgrp * 4 + j) * SEQ) * G3 + ncol0 + lrow;

    // prologue: gx for t=0
    uint32_t gxc[24], gxn[24];
    #pragma unroll
    for (int j = 0; j < 4; ++j) {
        const ushort* gp = gbase[j];
        #pragma unroll
        for (int g = 0; g < 3; ++g)
            #pragma unroll
            for (int n = 0; n < 2; ++n)
                gxc[g * 8 + n * 4 + j] = gp[g * HID + n * 16];
    }
    __syncthreads();

    for (int t = 0; t < SEQ; ++t) {
        // prefetch gx for t+1 (clamped; fully hidden under this step)
        int tn = (t + 1 < SEQ) ? t + 1 : t;
        #pragma unroll
        for (int j = 0; j < 4; ++j) {
            const ushort* gp = gbase[j] + (size_t)tn * G3;
            #pragma unroll
            for (int g = 0; g < 3; ++g)
                #pragma unroll
                for (int n = 0; n < 2; ++n)
                    gxn[g * 8 + n * 4 + j] = gp[g * HID + n * 16];
        }

        // ---- z/r GEMM (h-part only), acc seeded with gx ----
        f32x4 az[2], ar[2];
        #pragma unroll
        for (int n = 0; n < 2; ++n)
            #pragma unroll
            for (int j = 0; j < 4; ++j) {
                az[n][j] = bf2f(gxc[0 * 8 + n * 4 + j]);
                ar[n][j] = bf2f(gxc[1 * 8 + n * 4 + j]);
            }
        #pragma unroll
        for (int ks = 0; ks < 8; ++ks) {
            short8 a = *(const short8*)(HBF + lrow * 512 + ((ks * 64 + kgrp * 16) ^ ((lrow & 7) << 4)));
            az[0] = MFMA(a, Wz[ks][0], az[0]);
            az[1] = MFMA(a, Wz[ks][1], az[1]);
            ar[0] = MFMA(a, Wr[ks][0], ar[0]);
            ar[1] = MFMA(a, Wr[ks][1], ar[1]);
        }

        // epilogue-1: sigmoid, r*h -> LDS
        #pragma unroll
        for (int n = 0; n < 2; ++n) {
            int colg = ncol0 + n * 16 + lrow;
            #pragma unroll
            for (int j = 0; j < 4; ++j) {
                int row = kgrp * 4 + j;
                float zv = sigmoidf_(az[n][j]);
                az[n][j] = zv;
                float rv = sigmoidf_(ar[n][j]);
                *(ushort*)(RH + row * 512 + ((colg * 2) ^ ((row & 7) << 4))) = f2bf(rv * h[n][j]);
            }
        }
        __syncthreads();

        // ---- a GEMM: (r*h) @ Wh_a, acc seeded with gx_a ----
        f32x4 aa[2];
        #pragma unroll
        for (int n = 0; n < 2; ++n)
            #pragma unroll
            for (int j = 0; j < 4; ++j)
                aa[n][j] = bf2f(gxc[2 * 8 + n * 4 + j]);
        #pragma unroll
        for (int ks = 0; ks < 8; ++ks) {
            short8 a = *(const short8*)(RH + lrow * 512 + ((ks * 64 + kgrp * 16) ^ ((lrow & 7) << 4)));
            #pragma unroll
            for (int n = 0; n < 2; ++n) {
                int colg = ncol0 + n * 16 + lrow;
                short8 bw = *(const short8*)(WhA + colg * 512 + ((ks * 64 + kgrp * 16) ^ ((colg & 7) << 4)));
                aa[n] = MFMA(a, bw, aa[n]);
            }
        }

        // epilogue-2: tanh + h update + hbf -> LDS
        #pragma unroll
        for (int n = 0; n < 2; ++n) {
            int colg = ncol0 + n * 16 + lrow;
            #pragma unroll
            for (int j = 0; j < 4; ++j) {
                int row = kgrp * 4 + j;
                float av = tanhf_(aa[n][j]);
                float zv = az[n][j];
                float hn = (1.f - zv) * h[n][j] + zv * av;
                h[n][j] = hn;
                *(ushort*)(HBF + row * 512 + ((colg * 2) ^ ((row & 7) << 4))) = f2bf(hn);
            }
        }

        #pragma unroll
        for (int i = 0; i < 24; ++i) gxc[i] = gxn[i];
        __syncthreads();
    }

    // ---- projection: out = h @ w_p + b_p ----
    f32x4 ap[2] = {{0,0,0,0},{0,0,0,0}};
    #pragma unroll
    for (int ks = 0; ks < 8; ++ks) {
        short8 a = *(const short8*)(HBF + lrow * 512 + ((ks * 64 + kgrp * 16) ^ ((lrow & 7) << 4)));
        #pragma unroll
        for (int n = 0; n < 2; ++n) {
            int colg = ncol0 + n * 16 + lrow;
            short8 bw = *(const short8*)&WpT[(size_t)colg * HID + ks * 32 + kgrp * 8];
            ap[n] = MFMA(a, bw, ap[n]);
        }
    }
    #pragma unroll
    for (int n = 0; n < 2; ++n) {
        int colg = ncol0 + n * 16 + lrow;
        #pragma unroll
        for (int j = 0; j < 4; ++j) {
            int row = kgrp * 4 + j;
            out[(size_t)(r0 + row) * HID + colg] = ap[n][j] + bpr[n];
        }
    }
}

// ============ fallback (R2 kernel, known-good) if ws too small ============
#define F_WHA 0
#define F_XT  131072
#define F_HBF 139264
#define F_RH  147456
#define F_TOTAL 155648

__global__ __launch_bounds__(THREADS, 2) void gru_fallback(
    const int* __restrict__ x, const float* __restrict__ embed,
    const float* __restrict__ bias, const float* __restrict__ bp,
    const ushort* __restrict__ WiT, const ushort* __restrict__ WhT,
    const ushort* __restrict__ WpT, float* __restrict__ out)
{
    char* WhA = smem + F_WHA;
    char* XT  = smem + F_XT;
    char* HBF = smem + F_HBF;
    char* RH  = smem + F_RH;

    const int tid  = threadIdx.x;
    const int lane = tid & 63;
    const int wid  = tid >> 6;
    const int lrow = lane & 15;
    const int kgrp = lane >> 4;
    const int r0   = blockIdx.x * BM;
    const int ncol0 = wid * 32;
    const int grow = tid >> 5;
    const int gq   = tid & 31;

    for (int c = tid; c < 8192; c += THREADS) {
        int row = c >> 5, ch = c & 31;
        short8 v = *(const short8*)&WhT[(size_t)(2 * HID + row) * HID + ch * 8];
        *(short8*)(WhA + row * 512 + ((ch * 16) ^ ((row & 7) << 4))) = v;
    }
    *(short8*)(HBF + tid * 16) = (short8){0,0,0,0,0,0,0,0};
    {
        int tok = x[(r0 + grow) * SEQ + 0];
        float4 f = *(const float4*)&embed[(size_t)tok * WDIM + gq * 4];
        uint32_t p0 = f2bf(f.x) | ((uint32_t)f2bf(f.y) << 16);
        uint32_t p1 = f2bf(f.z) | ((uint32_t)f2bf(f.w) << 16);
        *(uint2*)(XT + grow * 256 + ((gq * 8) ^ ((grow & 7) << 4))) = (uint2){p0, p1};
    }

    short8 Wz[8][2], Wr[8][2];
    #pragma unroll
    for (int ks = 0; ks < 8; ++ks)
        #pragma unroll
        for (int n = 0; n < 2; ++n) {
            int colg = ncol0 + n * 16 + lrow;
            Wz[ks][n] = *(const short8*)&WhT[(size_t)colg * HID + ks * 32 + kgrp * 8];
            Wr[ks][n] = *(const short8*)&WhT[(size_t)(HID + colg) * HID + ks * 32 + kgrp * 8];
            asm volatile("" : "+v"(Wz[ks][n]), "+v"(Wr[ks][n]));
        }

    float bzr[2], brr[2], bar[2], bpr[2];
    #pragma unroll
    for (int n = 0; n < 2; ++n) {
        int colg = ncol0 + n * 16 + lrow;
        bzr[n] = bias[colg];
        brr[n] = bias[HID + colg];
        bar[n] = bias[2 * HID + colg];
        bpr[n] = bp[colg];
    }

    float h[2][4] = {{0.f,0.f,0.f,0.f},{0.f,0.f,0.f,0.f}};
    uint32_t zz = 0;

    __syncthreads();

    for (int t = 0; t < SEQ; ++t) {
        char* xt = XT + (t & 1) * 4096;
        char* xn = XT + ((t + 1) & 1) * 4096;

        asm volatile("" : "+v"(zz));
        const ushort* wiB = WiT + zz;

        int tp = (t + 1 < SEQ) ? t + 1 : SEQ - 1;
        int tok = x[(r0 + grow) * SEQ + tp];

        f32x4 az[2] = {{0,0,0,0},{0,0,0,0}};
        f32x4 ar[2] = {{0,0,0,0},{0,0,0,0}};

        #pragma unroll
        for (int ks = 0; ks < 4; ++ks) {
            short8 a = *(const short8*)(xt + lrow * 256 + ((ks * 64 + kgrp * 16) ^ ((lrow & 7) << 4)));
            #pragma unroll
            for (int n = 0; n < 2; ++n) {
                int colg = ncol0 + n * 16 + lrow;
                short8 bz = *(const short8*)&wiB[(size_t)colg * WDIM + ks * 32 + kgrp * 8];
                short8 br = *(const short8*)&wiB[(size_t)(HID + colg) * WDIM + ks * 32 + kgrp * 8];
                az[n] = MFMA(a, bz, az[n]);
                ar[n] = MFMA(a, br, ar[n]);
            }
        }
        #pragma unroll
        for (int ks = 0; ks < 8; ++ks) {
            short8 a = *(const short8*)(HBF + lrow * 512 + ((ks * 64 + kgrp * 16) ^ ((lrow & 7) << 4)));
            az[0] = MFMA(a, Wz[ks][0], az[0]);
            az[1] = MFMA(a, Wz[ks][1], az[1]);
            ar[0] = MFMA(a, Wr[ks][0], ar[0]);
            ar[1] = MFMA(a, Wr[ks][1], ar[1]);
        }

        float4 ef = *(const float4*)&embed[(size_t)tok * WDIM + gq * 4];

        #pragma unroll
        for (int n = 0; n < 2; ++n) {
            int colg = ncol0 + n * 16 + lrow;
            #pragma unroll
            for (int j = 0; j < 4; ++j) {
                int row = kgrp * 4 + j;
                float zv = sigmoidf_(az[n][j] + bzr[n]);
                az[n][j] = zv;
                float rv = sigmoidf_(ar[n][j] + brr[n]);
                *(ushort*)(RH + row * 512 + ((colg * 2) ^ ((row & 7) << 4))) = f2bf(rv * h[n][j]);
            }
        }
        __syncthreads();

        f32x4 aa[2] = {{0,0,0,0},{0,0,0,0}};
        #pragma unroll
        for (int ks = 0; ks < 4; ++ks) {
            short8 a = *(const short8*)(xt + lrow * 256 + ((ks * 64 + kgrp * 16) ^ ((lrow & 7) << 4)));
            #pragma unroll
            for (int n = 0; n < 2; ++n) {
                int colg = ncol0 + n * 16 + lrow;
                short8 bw = *(const short8*)&wiB[(size_t)(2 * HID + colg) * WDIM + ks * 32 + kgrp * 8];
                aa[n] = MFMA(a, bw, aa[n]);
            }
        }
        #pragma unroll
        for (int ks = 0; ks < 8; ++ks) {
            short8 a = *(const short8*)(RH + lrow * 512 + ((ks * 64 + kgrp * 16) ^ ((lrow & 7) << 4)));
            #pragma unroll
            for (int n = 0; n < 2; ++n) {
                int colg = ncol0 + n * 16 + lrow;
                short8 bw = *(const short8*)(WhA + colg * 512 + ((ks * 64 + kgrp * 16) ^ ((colg & 7) << 4)));
                aa[n] = MFMA(a, bw, aa[n]);
            }
        }

        #pragma unroll
        for (int n = 0; n < 2; ++n) {
            int colg = ncol0 + n * 16 + lrow;
            #pragma unroll
            for (int j = 0; j < 4; ++j) {
                int row = kgrp * 4 + j;
                float av = tanhf_(aa[n][j] + bar[n]);
                float zv = az[n][j];
                float hn = (1.f - zv) * h[n][j] + zv * av;
                h[n][j] = hn;
                *(ushort*)(HBF + row * 512 + ((colg * 2) ^ ((row & 7) << 4))) = f2bf(hn);
            }
        }

        {
            uint32_t p0 = f2bf(ef.x) | ((uint32_t)f2bf(ef.y) << 16);
            uint32_t p1 = f2bf(ef.z) | ((uint32_t)f2bf(ef.w) << 16);
            *(uint2*)(xn + grow * 256 + ((gq * 8) ^ ((grow & 7) << 4))) = (uint2){p0, p1};
        }
        __syncthreads();
    }

    f32x4 ap[2] = {{0,0,0,0},{0,0,0,0}};
    #pragma unroll
    for (int ks = 0; ks < 8; ++ks) {
        short8 a = *(const short8*)(HBF + lrow * 512 + ((ks * 64 + kgrp * 16) ^ ((lrow & 7) << 4)));
        #pragma unroll
        for (int n = 0; n < 2; ++n) {
            int colg = ncol0 + n * 16 + lrow;
            short8 bw = *(const short8*)&WpT[(size_t)colg * HID + ks * 32 + kgrp * 8];
            ap[n] = MFMA(a, bw, ap[n]);
        }
    }
    #pragma unroll
    for (int n = 0; n < 2; ++n) {
        int colg = ncol0 + n * 16 + lrow;
        #pragma unroll
        for (int j = 0; j < 4; ++j) {
            int row = kgrp * 4 + j;
            out[(size_t)(r0 + row) * HID + colg] = ap[n][j] + bpr[n];
        }
    }
}

extern "C" void kernel_launch(void* const* d_in, const int* in_sizes, int n_in,
                              void* d_out, int out_size, void* d_ws, size_t ws_size,
                              hipStream_t stream) {
    const int*   x     = (const int*)d_in[0];
    const float* embed = (const float*)d_in[1];
    const float* wi    = (const float*)d_in[2];
    const float* wh    = (const float*)d_in[3];
    const float* b     = (const float*)d_in[4];
    const float* wp    = (const float*)d_in[5];
    const float* bp    = (const float*)d_in[6];
    float* out = (float*)d_out;
    ushort* ws = (ushort*)d_ws;

    (void)hipFuncSetAttribute((const void*)gru_rec,
                              hipFuncAttributeMaxDynamicSharedMemorySize, R_TOTAL);
    (void)hipFuncSetAttribute((const void*)gru_fallback,
                              hipFuncAttributeMaxDynamicSharedMemorySize, F_TOTAL);

    hipLaunchKernelGGL(prep_kernel, dim3((WS_WTOTAL + 255) / 256), dim3(256), 0, stream,
                       wi, wh, wp, ws);

    if (ws_size >= WS_NEEDED) {
        ushort* gxp = ws + WS_GX;
        hipLaunchKernelGGL(gx_kernel, dim3((BATCH * SEQ) / GXM, G3 / GXN), dim3(256), 0, stream,
                           x, embed, b, ws + WS_WIT, gxp);
        hipLaunchKernelGGL(gru_rec, dim3(BATCH / BM), dim3(THREADS), R_TOTAL, stream,
                           gxp, bp, ws + WS_WHT, ws + WS_WPT, out);
    } else {
        hipLaunchKernelGGL(gru_fallback, dim3(BATCH / BM), dim3(THREADS), F_TOTAL, stream,
                           x, embed, b, bp, ws + WS_WIT, ws + WS_WHT, ws + WS_WPT, out);
    }
}

// Round 4
// 223.382 us; speedup vs baseline: 1.5048x; 1.5048x over previous
//
#include <hip/hip_runtime.h>
#include <stdint.h>

#define WDIM 128
#define HID 256
#define G3 768
#define VOCAB 50257
#define EGROWS 50304          // 786 * 64
#define BATCH 4096
#define SEQ 32
#define BM 16
#define THREADS 512

// ws layout (ushort units): WiT[768][128], WhT[768][256], WpT[256][256], EG[50304][768]
#define WS_WIT 0
#define WS_WHT 98304
#define WS_WPT 294912
#define WS_WTOTAL 360448
#define WS_EG  362496ULL      // byte offset 724992
#define WS_NEEDED (724992ULL + (unsigned long long)EGROWS * G3 * 2ULL)

typedef __attribute__((ext_vector_type(8))) short short8;
typedef __attribute__((ext_vector_type(4))) float f32x4;

#define MFMA(a, b, c) __builtin_amdgcn_mfma_f32_16x16x32_bf16((a), (b), (c), 0, 0, 0)

__device__ __forceinline__ ushort f2bf(float f) {
    union { float f; uint32_t u; } v; v.f = f;
    uint32_t u = v.u;
    u += 0x7fffu + ((u >> 16) & 1u);   // RNE
    return (ushort)(u >> 16);
}
__device__ __forceinline__ float bf2f(uint32_t b) {
    union { uint32_t u; float f; } v; v.u = b << 16; return v.f;
}
__device__ __forceinline__ float sigmoidf_(float x) {
    return __builtin_amdgcn_rcpf(1.f + __expf(-x));
}
__device__ __forceinline__ float tanhf_(float x) {
    float e2 = __expf(2.f * x);
    return 1.f - 2.f * __builtin_amdgcn_rcpf(e2 + 1.f);
}

__global__ void prep_kernel(const float* __restrict__ wi, const float* __restrict__ wh,
                            const float* __restrict__ wp, ushort* __restrict__ ws) {
    int gid = blockIdx.x * blockDim.x + threadIdx.x;
    if (gid < G3 * WDIM) {
        int n = gid / WDIM, k = gid % WDIM;
        ws[WS_WIT + n * WDIM + k] = f2bf(wi[k * G3 + n]);
    } else if (gid < G3 * WDIM + G3 * HID) {
        int g = gid - G3 * WDIM;
        int n = g / HID, k = g % HID;
        ws[WS_WHT + n * HID + k] = f2bf(wh[k * G3 + n]);
    } else if (gid < G3 * WDIM + G3 * HID + HID * HID) {
        int g = gid - G3 * WDIM - G3 * HID;
        int n = g / HID, k = g % HID;
        ws[WS_WPT + n * HID + k] = f2bf(wp[k * HID + n]);
    }
}

// ============ EG = bf16( embed @ Wi + b ) : M=50304, N=768, K=128 ============
// Paired even/odd col fragments -> dword stores (64B contiguous / 16 lanes).
#define EGM 64
#define EGN 128

__global__ __launch_bounds__(256, 4) void eg_kernel(
    const float* __restrict__ embed, const float* __restrict__ bias,
    const ushort* __restrict__ WiT, ushort* __restrict__ EG)
{
    __shared__ char At[16384];           // [64 rows][256B] bf16, XOR-swizzled
    const int tid  = threadIdx.x;
    const int lane = tid & 63, wid = tid >> 6;
    const int lrow = lane & 15, kgrp = lane >> 4;
    const int m0  = blockIdx.x * EGM;
    const int nc0 = blockIdx.y * EGN;

    {   // stream 64 embedding rows -> LDS bf16 (4 threads/row, 32 floats each)
        int row = tid >> 2, part = tid & 3;
        int er = m0 + row; if (er >= VOCAB) er = VOCAB - 1;
        const float* e = embed + (size_t)er * WDIM + part * 32;
        #pragma unroll
        for (int q = 0; q < 8; ++q) {
            float4 f = ((const float4*)e)[q];
            uint32_t p0 = f2bf(f.x) | ((uint32_t)f2bf(f.y) << 16);
            uint32_t p1 = f2bf(f.z) | ((uint32_t)f2bf(f.w) << 16);
            *(uint2*)(At + row * 256 + ((part * 64 + q * 8) ^ ((row & 7) << 4))) = (uint2){p0, p1};
        }
    }
    __syncthreads();

    f32x4 acc[8];
    #pragma unroll
    for (int n = 0; n < 8; ++n) acc[n] = (f32x4){0,0,0,0};

    // fragment n = 2*i + s covers global col nc0 + 32*i + 2*c + s  (c = lane&15)
    const int arow = wid * 16 + lrow;
    #pragma unroll
    for (int ks = 0; ks < 4; ++ks) {
        short8 a = *(const short8*)(At + arow * 256 + ((ks * 64 + kgrp * 16) ^ ((arow & 7) << 4)));
        #pragma unroll
        for (int n = 0; n < 8; ++n) {
            int colg = nc0 + 32 * (n >> 1) + 2 * lrow + (n & 1);
            short8 b = *(const short8*)&WiT[(size_t)colg * WDIM + ks * 32 + kgrp * 8];
            acc[n] = MFMA(a, b, acc[n]);
        }
    }

    float bv[8];
    #pragma unroll
    for (int n = 0; n < 8; ++n) bv[n] = bias[nc0 + 32 * (n >> 1) + 2 * lrow + (n & 1)];

    #pragma unroll
    for (int i = 0; i < 4; ++i)
        #pragma unroll
        for (int j = 0; j < 4; ++j) {
            size_t m = (size_t)(m0 + wid * 16 + kgrp * 4 + j);
            uint32_t pk = (uint32_t)f2bf(acc[2 * i][j] + bv[2 * i])
                        | ((uint32_t)f2bf(acc[2 * i + 1][j] + bv[2 * i + 1]) << 16);
            *(uint32_t*)&EG[m * G3 + nc0 + 32 * i + 2 * lrow] = pk;
        }
}

// ============ recurrent kernel: h-part only, EG gathered+prefetched ============
#define R_WHA 0          // Wh_a swizzled [256 cols][512B]  (128KB)
#define R_HBF 131072     // [16][512B] bf16 h, swizzled
#define R_RH  139264     // [16][512B] bf16 r*h, swizzled
#define R_TOK 147456     // [16][32] int tokens (2KB)
#define R_TOTAL 149504

extern __shared__ char smem[];

#define GRU_STEP(T, GC, GN) do {                                              \
    int tn = ((T) + 1 < SEQ) ? (T) + 1 : SEQ - 1;                             \
    _Pragma("unroll")                                                         \
    for (int j = 0; j < 4; ++j) {                                             \
        int tok = tokL[(kgrp * 4 + j) * SEQ + tn];                            \
        const ushort* gp = EG + (size_t)tok * G3 + ncol0 + lrow;              \
        _Pragma("unroll")                                                     \
        for (int g = 0; g < 3; ++g)                                           \
            _Pragma("unroll")                                                 \
            for (int n = 0; n < 2; ++n)                                       \
                GN[g * 8 + n * 4 + j] = gp[g * HID + n * 16];                 \
    }                                                                         \
    f32x4 az[2], ar[2];                                                       \
    _Pragma("unroll")                                                         \
    for (int n = 0; n < 2; ++n)                                               \
        _Pragma("unroll")                                                     \
        for (int j = 0; j < 4; ++j) {                                         \
            az[n][j] = bf2f(GC[0 * 8 + n * 4 + j]);                           \
            ar[n][j] = bf2f(GC[1 * 8 + n * 4 + j]);                           \
        }                                                                     \
    _Pragma("unroll")                                                         \
    for (int ks = 0; ks < 8; ++ks) {                                          \
        short8 a = *(const short8*)(HBF + lrow * 512 + ((ks * 64 + kgrp * 16) ^ ((lrow & 7) << 4))); \
        az[0] = MFMA(a, Wz[ks][0], az[0]);                                    \
        az[1] = MFMA(a, Wz[ks][1], az[1]);                                    \
        ar[0] = MFMA(a, Wr[ks][0], ar[0]);                                    \
        ar[1] = MFMA(a, Wr[ks][1], ar[1]);                                    \
    }                                                                         \
    _Pragma("unroll")                                                         \
    for (int n = 0; n < 2; ++n) {                                             \
        int colg = ncol0 + n * 16 + lrow;                                     \
        _Pragma("unroll")                                                     \
        for (int j = 0; j < 4; ++j) {                                         \
            int row = kgrp * 4 + j;                                           \
            float zv = sigmoidf_(az[n][j]);                                   \
            az[n][j] = zv;                                                    \
            float rv = sigmoidf_(ar[n][j]);                                   \
            *(ushort*)(RH + row * 512 + ((colg * 2) ^ ((row & 7) << 4))) = f2bf(rv * h[n][j]); \
        }                                                                     \
    }                                                                         \
    __syncthreads();                                                          \
    f32x4 aa[2];                                                              \
    _Pragma("unroll")                                                         \
    for (int n = 0; n < 2; ++n)                                               \
        _Pragma("unroll")                                                     \
        for (int j = 0; j < 4; ++j)                                           \
            aa[n][j] = bf2f(GC[2 * 8 + n * 4 + j]);                           \
    _Pragma("unroll")                                                         \
    for (int ks = 0; ks < 8; ++ks) {                                          \
        short8 a = *(const short8*)(RH + lrow * 512 + ((ks * 64 + kgrp * 16) ^ ((lrow & 7) << 4))); \
        _Pragma("unroll")                                                     \
        for (int n = 0; n < 2; ++n) {                                         \
            int colg = ncol0 + n * 16 + lrow;                                 \
            short8 bw = *(const short8*)(WhA + colg * 512 + ((ks * 64 + kgrp * 16) ^ ((colg & 7) << 4))); \
            aa[n] = MFMA(a, bw, aa[n]);                                       \
        }                                                                     \
    }                                                                         \
    _Pragma("unroll")                                                         \
    for (int n = 0; n < 2; ++n) {                                             \
        int colg = ncol0 + n * 16 + lrow;                                     \
        _Pragma("unroll")                                                     \
        for (int j = 0; j < 4; ++j) {                                         \
            int row = kgrp * 4 + j;                                           \
            float av = tanhf_(aa[n][j]);                                      \
            float zv = az[n][j];                                              \
            float hn = (1.f - zv) * h[n][j] + zv * av;                        \
            h[n][j] = hn;                                                     \
            *(ushort*)(HBF + row * 512 + ((colg * 2) ^ ((row & 7) << 4))) = f2bf(hn); \
        }                                                                     \
    }                                                                         \
    __syncthreads();                                                          \
} while (0)

__global__ __launch_bounds__(THREADS, 2) void gru_rec(
    const int* __restrict__ x, const ushort* __restrict__ EG,
    const float* __restrict__ bp, const ushort* __restrict__ WhT,
    const ushort* __restrict__ WpT, float* __restrict__ out)
{
    char* WhA = smem + R_WHA;
    char* HBF = smem + R_HBF;
    char* RH  = smem + R_RH;
    int*  tokL = (int*)(smem + R_TOK);

    const int tid  = threadIdx.x;
    const int lane = tid & 63;
    const int wid  = tid >> 6;
    const int lrow = lane & 15;
    const int kgrp = lane >> 4;
    const int r0   = blockIdx.x * BM;
    const int ncol0 = wid * 32;

    // one-time LDS fill: Wh_a swizzled
    for (int c = tid; c < 8192; c += THREADS) {
        int row = c >> 5, ch = c & 31;
        short8 v = *(const short8*)&WhT[(size_t)(2 * HID + row) * HID + ch * 8];
        *(short8*)(WhA + row * 512 + ((ch * 16) ^ ((row & 7) << 4))) = v;
    }
    *(short8*)(HBF + tid * 16) = (short8){0,0,0,0,0,0,0,0};
    tokL[tid] = x[r0 * SEQ + tid];       // 16 rows x 32 steps

    // resident Wh z/r fragments (128 VGPR), pinned against rematerialization
    short8 Wz[8][2], Wr[8][2];
    #pragma unroll
    for (int ks = 0; ks < 8; ++ks)
        #pragma unroll
        for (int n = 0; n < 2; ++n) {
            int colg = ncol0 + n * 16 + lrow;
            Wz[ks][n] = *(const short8*)&WhT[(size_t)colg * HID + ks * 32 + kgrp * 8];
            Wr[ks][n] = *(const short8*)&WhT[(size_t)(HID + colg) * HID + ks * 32 + kgrp * 8];
            asm volatile("" : "+v"(Wz[ks][n]), "+v"(Wr[ks][n]));
        }

    float bpr[2];
    #pragma unroll
    for (int n = 0; n < 2; ++n) bpr[n] = bp[ncol0 + n * 16 + lrow];

    float h[2][4] = {{0.f,0.f,0.f,0.f},{0.f,0.f,0.f,0.f}};

    __syncthreads();

    // prologue: gather EG rows for t=0
    uint32_t gxA[24], gxB[24];
    #pragma unroll
    for (int j = 0; j < 4; ++j) {
        int tok = tokL[(kgrp * 4 + j) * SEQ + 0];
        const ushort* gp = EG + (size_t)tok * G3 + ncol0 + lrow;
        #pragma unroll
        for (int g = 0; g < 3; ++g)
            #pragma unroll
            for (int n = 0; n < 2; ++n)
                gxA[g * 8 + n * 4 + j] = gp[g * HID + n * 16];
    }

    for (int t = 0; t < SEQ; t += 2) {
        GRU_STEP(t,     gxA, gxB);
        GRU_STEP(t + 1, gxB, gxA);
    }

    // ---- projection: out = h @ w_p + b_p ----
    f32x4 ap[2] = {{0,0,0,0},{0,0,0,0}};
    #pragma unroll
    for (int ks = 0; ks < 8; ++ks) {
        short8 a = *(const short8*)(HBF + lrow * 512 + ((ks * 64 + kgrp * 16) ^ ((lrow & 7) << 4)));
        #pragma unroll
        for (int n = 0; n < 2; ++n) {
            int colg = ncol0 + n * 16 + lrow;
            short8 bw = *(const short8*)&WpT[(size_t)colg * HID + ks * 32 + kgrp * 8];
            ap[n] = MFMA(a, bw, ap[n]);
        }
    }
    #pragma unroll
    for (int n = 0; n < 2; ++n) {
        int colg = ncol0 + n * 16 + lrow;
        #pragma unroll
        for (int j = 0; j < 4; ++j) {
            int row = kgrp * 4 + j;
            out[(size_t)(r0 + row) * HID + colg] = ap[n][j] + bpr[n];
        }
    }
}

// ============ fallback (R2 kernel, known-good) if ws too small ============
#define F_WHA 0
#define F_XT  131072
#define F_HBF 139264
#define F_RH  147456
#define F_TOTAL 155648

__global__ __launch_bounds__(THREADS, 2) void gru_fallback(
    const int* __restrict__ x, const float* __restrict__ embed,
    const float* __restrict__ bias, const float* __restrict__ bp,
    const ushort* __restrict__ WiT, const ushort* __restrict__ WhT,
    const ushort* __restrict__ WpT, float* __restrict__ out)
{
    char* WhA = smem + F_WHA;
    char* XT  = smem + F_XT;
    char* HBF = smem + F_HBF;
    char* RH  = smem + F_RH;

    const int tid  = threadIdx.x;
    const int lane = tid & 63;
    const int wid  = tid >> 6;
    const int lrow = lane & 15;
    const int kgrp = lane >> 4;
    const int r0   = blockIdx.x * BM;
    const int ncol0 = wid * 32;
    const int grow = tid >> 5;
    const int gq   = tid & 31;

    for (int c = tid; c < 8192; c += THREADS) {
        int row = c >> 5, ch = c & 31;
        short8 v = *(const short8*)&WhT[(size_t)(2 * HID + row) * HID + ch * 8];
        *(short8*)(WhA + row * 512 + ((ch * 16) ^ ((row & 7) << 4))) = v;
    }
    *(short8*)(HBF + tid * 16) = (short8){0,0,0,0,0,0,0,0};
    {
        int tok = x[(r0 + grow) * SEQ + 0];
        float4 f = *(const float4*)&embed[(size_t)tok * WDIM + gq * 4];
        uint32_t p0 = f2bf(f.x) | ((uint32_t)f2bf(f.y) << 16);
        uint32_t p1 = f2bf(f.z) | ((uint32_t)f2bf(f.w) << 16);
        *(uint2*)(XT + grow * 256 + ((gq * 8) ^ ((grow & 7) << 4))) = (uint2){p0, p1};
    }

    short8 Wz[8][2], Wr[8][2];
    #pragma unroll
    for (int ks = 0; ks < 8; ++ks)
        #pragma unroll
        for (int n = 0; n < 2; ++n) {
            int colg = ncol0 + n * 16 + lrow;
            Wz[ks][n] = *(const short8*)&WhT[(size_t)colg * HID + ks * 32 + kgrp * 8];
            Wr[ks][n] = *(const short8*)&WhT[(size_t)(HID + colg) * HID + ks * 32 + kgrp * 8];
            asm volatile("" : "+v"(Wz[ks][n]), "+v"(Wr[ks][n]));
        }

    float bzr[2], brr[2], bar[2], bpr[2];
    #pragma unroll
    for (int n = 0; n < 2; ++n) {
        int colg = ncol0 + n * 16 + lrow;
        bzr[n] = bias[colg];
        brr[n] = bias[HID + colg];
        bar[n] = bias[2 * HID + colg];
        bpr[n] = bp[colg];
    }

    float h[2][4] = {{0.f,0.f,0.f,0.f},{0.f,0.f,0.f,0.f}};
    uint32_t zz = 0;

    __syncthreads();

    for (int t = 0; t < SEQ; ++t) {
        char* xt = XT + (t & 1) * 4096;
        char* xn = XT + ((t + 1) & 1) * 4096;

        asm volatile("" : "+v"(zz));
        const ushort* wiB = WiT + zz;

        int tp = (t + 1 < SEQ) ? t + 1 : SEQ - 1;
        int tok = x[(r0 + grow) * SEQ + tp];

        f32x4 az[2] = {{0,0,0,0},{0,0,0,0}};
        f32x4 ar[2] = {{0,0,0,0},{0,0,0,0}};

        #pragma unroll
        for (int ks = 0; ks < 4; ++ks) {
            short8 a = *(const short8*)(xt + lrow * 256 + ((ks * 64 + kgrp * 16) ^ ((lrow & 7) << 4)));
            #pragma unroll
            for (int n = 0; n < 2; ++n) {
                int colg = ncol0 + n * 16 + lrow;
                short8 bz = *(const short8*)&wiB[(size_t)colg * WDIM + ks * 32 + kgrp * 8];
                short8 br = *(const short8*)&wiB[(size_t)(HID + colg) * WDIM + ks * 32 + kgrp * 8];
                az[n] = MFMA(a, bz, az[n]);
                ar[n] = MFMA(a, br, ar[n]);
            }
        }
        #pragma unroll
        for (int ks = 0; ks < 8; ++ks) {
            short8 a = *(const short8*)(HBF + lrow * 512 + ((ks * 64 + kgrp * 16) ^ ((lrow & 7) << 4)));
            az[0] = MFMA(a, Wz[ks][0], az[0]);
            az[1] = MFMA(a, Wz[ks][1], az[1]);
            ar[0] = MFMA(a, Wr[ks][0], ar[0]);
            ar[1] = MFMA(a, Wr[ks][1], ar[1]);
        }

        float4 ef = *(const float4*)&embed[(size_t)tok * WDIM + gq * 4];

        #pragma unroll
        for (int n = 0; n < 2; ++n) {
            int colg = ncol0 + n * 16 + lrow;
            #pragma unroll
            for (int j = 0; j < 4; ++j) {
                int row = kgrp * 4 + j;
                float zv = sigmoidf_(az[n][j] + bzr[n]);
                az[n][j] = zv;
                float rv = sigmoidf_(ar[n][j] + brr[n]);
                *(ushort*)(RH + row * 512 + ((colg * 2) ^ ((row & 7) << 4))) = f2bf(rv * h[n][j]);
            }
        }
        __syncthreads();

        f32x4 aa[2] = {{0,0,0,0},{0,0,0,0}};
        #pragma unroll
        for (int ks = 0; ks < 4; ++ks) {
            short8 a = *(const short8*)(xt + lrow * 256 + ((ks * 64 + kgrp * 16) ^ ((lrow & 7) << 4)));
            #pragma unroll
            for (int n = 0; n < 2; ++n) {
                int colg = ncol0 + n * 16 + lrow;
                short8 bw = *(const short8*)&wiB[(size_t)(2 * HID + colg) * WDIM + ks * 32 + kgrp * 8];
                aa[n] = MFMA(a, bw, aa[n]);
            }
        }
        #pragma unroll
        for (int ks = 0; ks < 8; ++ks) {
            short8 a = *(const short8*)(RH + lrow * 512 + ((ks * 64 + kgrp * 16) ^ ((lrow & 7) << 4)));
            #pragma unroll
            for (int n = 0; n < 2; ++n) {
                int colg = ncol0 + n * 16 + lrow;
                short8 bw = *(const short8*)(WhA + colg * 512 + ((ks * 64 + kgrp * 16) ^ ((colg & 7) << 4)));
                aa[n] = MFMA(a, bw, aa[n]);
            }
        }

        #pragma unroll
        for (int n = 0; n < 2; ++n) {
            int colg = ncol0 + n * 16 + lrow;
            #pragma unroll
            for (int j = 0; j < 4; ++j) {
                int row = kgrp * 4 + j;
                float av = tanhf_(aa[n][j] + bar[n]);
                float zv = az[n][j];
                float hn = (1.f - zv) * h[n][j] + zv * av;
                h[n][j] = hn;
                *(ushort*)(HBF + row * 512 + ((colg * 2) ^ ((row & 7) << 4))) = f2bf(hn);
            }
        }

        {
            uint32_t p0 = f2bf(ef.x) | ((uint32_t)f2bf(ef.y) << 16);
            uint32_t p1 = f2bf(ef.z) | ((uint32_t)f2bf(ef.w) << 16);
            *(uint2*)(xn + grow * 256 + ((gq * 8) ^ ((grow & 7) << 4))) = (uint2){p0, p1};
        }
        __syncthreads();
    }

    f32x4 ap[2] = {{0,0,0,0},{0,0,0,0}};
    #pragma unroll
    for (int ks = 0; ks < 8; ++ks) {
        short8 a = *(const short8*)(HBF + lrow * 512 + ((ks * 64 + kgrp * 16) ^ ((lrow & 7) << 4)));
        #pragma unroll
        for (int n = 0; n < 2; ++n) {
            int colg = ncol0 + n * 16 + lrow;
            short8 bw = *(const short8*)&WpT[(size_t)colg * HID + ks * 32 + kgrp * 8];
            ap[n] = MFMA(a, bw, ap[n]);
        }
    }
    #pragma unroll
    for (int n = 0; n < 2; ++n) {
        int colg = ncol0 + n * 16 + lrow;
        #pragma unroll
        for (int j = 0; j < 4; ++j) {
            int row = kgrp * 4 + j;
            out[(size_t)(r0 + row) * HID + colg] = ap[n][j] + bpr[n];
        }
    }
}

extern "C" void kernel_launch(void* const* d_in, const int* in_sizes, int n_in,
                              void* d_out, int out_size, void* d_ws, size_t ws_size,
                              hipStream_t stream) {
    const int*   x     = (const int*)d_in[0];
    const float* embed = (const float*)d_in[1];
    const float* wi    = (const float*)d_in[2];
    const float* wh    = (const float*)d_in[3];
    const float* b     = (const float*)d_in[4];
    const float* wp    = (const float*)d_in[5];
    const float* bp    = (const float*)d_in[6];
    float* out = (float*)d_out;
    ushort* ws = (ushort*)d_ws;

    (void)hipFuncSetAttribute((const void*)gru_rec,
                              hipFuncAttributeMaxDynamicSharedMemorySize, R_TOTAL);
    (void)hipFuncSetAttribute((const void*)gru_fallback,
                              hipFuncAttributeMaxDynamicSharedMemorySize, F_TOTAL);

    hipLaunchKernelGGL(prep_kernel, dim3((WS_WTOTAL + 255) / 256), dim3(256), 0, stream,
                       wi, wh, wp, ws);

    if (ws_size >= WS_NEEDED) {
        ushort* eg = ws + WS_EG;
        hipLaunchKernelGGL(eg_kernel, dim3(EGROWS / EGM, G3 / EGN), dim3(256), 0, stream,
                           embed, b, ws + WS_WIT, eg);
        hipLaunchKernelGGL(gru_rec, dim3(BATCH / BM), dim3(THREADS), R_TOTAL, stream,
                           x, eg, bp, ws + WS_WHT, ws + WS_WPT, out);
    } else {
        hipLaunchKernelGGL(gru_fallback, dim3(BATCH / BM), dim3(THREADS), F_TOTAL, stream,
                           x, embed, b, bp, ws + WS_WIT, ws + WS_WHT, ws + WS_WPT, out);
    }
}

// Round 5
// 218.232 us; speedup vs baseline: 1.5403x; 1.0236x over previous
//
#include <hip/hip_runtime.h>
#include <stdint.h>

#define WDIM 128
#define HID 256
#define G3 768
#define VOCAB 50257
#define EGROWS 50304          // 786 * 64
#define BATCH 4096
#define SEQ 32
#define BM 16
#define THREADS 512

// ws layout (ushort units): WiT[768][128], WhT[768][256], WpT[256][256], EG[50304][768]
#define WS_WIT 0
#define WS_WHT 98304
#define WS_WPT 294912
#define WS_WTOTAL 360448
#define WS_EG  362496ULL      // byte offset 724992
#define WS_NEEDED (724992ULL + (unsigned long long)EGROWS * G3 * 2ULL)

typedef __attribute__((ext_vector_type(8))) short short8;
typedef __attribute__((ext_vector_type(4))) float f32x4;

#define MFMA(a, b, c) __builtin_amdgcn_mfma_f32_16x16x32_bf16((a), (b), (c), 0, 0, 0)

__device__ __forceinline__ ushort f2bf(float f) {
    union { float f; uint32_t u; } v; v.f = f;
    uint32_t u = v.u;
    u += 0x7fffu + ((u >> 16) & 1u);   // RNE
    return (ushort)(u >> 16);
}
__device__ __forceinline__ float bf2f_lo(uint32_t p) {
    union { uint32_t u; float f; } v; v.u = p << 16; return v.f;
}
__device__ __forceinline__ float bf2f_hi(uint32_t p) {
    union { uint32_t u; float f; } v; v.u = p & 0xffff0000u; return v.f;
}
__device__ __forceinline__ float sigmoidf_(float x) {
    return __builtin_amdgcn_rcpf(1.f + __expf(-x));
}
__device__ __forceinline__ float tanhf_(float x) {
    float e2 = __expf(2.f * x);
    return 1.f - 2.f * __builtin_amdgcn_rcpf(e2 + 1.f);
}

__global__ void prep_kernel(const float* __restrict__ wi, const float* __restrict__ wh,
                            const float* __restrict__ wp, ushort* __restrict__ ws) {
    int gid = blockIdx.x * blockDim.x + threadIdx.x;
    if (gid < G3 * WDIM) {
        int n = gid / WDIM, k = gid % WDIM;
        ws[WS_WIT + n * WDIM + k] = f2bf(wi[k * G3 + n]);
    } else if (gid < G3 * WDIM + G3 * HID) {
        int g = gid - G3 * WDIM;
        int n = g / HID, k = g % HID;
        ws[WS_WHT + n * HID + k] = f2bf(wh[k * G3 + n]);
    } else if (gid < G3 * WDIM + G3 * HID + HID * HID) {
        int g = gid - G3 * WDIM - G3 * HID;
        int n = g / HID, k = g % HID;
        ws[WS_WPT + n * HID + k] = f2bf(wp[k * HID + n]);
    }
}

// ============ EG = bf16( embed @ Wi + b ) : M=50304, N=768, K=128 ============
// One pass over embed per block; 6 N-chunks looped inside.
// Pair-store: dword at ushort idx m*768 + nc0 + 32*i + 2*lrow holds
//   lo = col nc0+32i+lrow, hi = col nc0+32i+16+lrow  (the gru gather unit).
#define EGM 64

__global__ __launch_bounds__(256, 4) void eg_kernel(
    const float* __restrict__ embed, const float* __restrict__ bias,
    const ushort* __restrict__ WiT, ushort* __restrict__ EG)
{
    __shared__ char At[16384];           // [64 rows][256B] bf16, XOR-swizzled
    const int tid  = threadIdx.x;
    const int lane = tid & 63, wid = tid >> 6;
    const int lrow = lane & 15, kgrp = lane >> 4;
    const int m0  = blockIdx.x * EGM;

    {   // stage 64 embedding rows -> LDS bf16 (4 threads/row, 32 floats each)
        int row = tid >> 2, part = tid & 3;
        int er = m0 + row; if (er >= VOCAB) er = VOCAB - 1;
        const float* e = embed + (size_t)er * WDIM + part * 32;
        #pragma unroll
        for (int q = 0; q < 8; ++q) {
            float4 f = ((const float4*)e)[q];
            uint32_t p0 = f2bf(f.x) | ((uint32_t)f2bf(f.y) << 16);
            uint32_t p1 = f2bf(f.z) | ((uint32_t)f2bf(f.w) << 16);
            *(uint2*)(At + row * 256 + ((part * 64 + q * 8) ^ ((row & 7) << 4))) = (uint2){p0, p1};
        }
    }
    __syncthreads();

    // hoist A-frags to regs (read LDS once)
    const int arow = wid * 16 + lrow;
    short8 afr[4];
    #pragma unroll
    for (int ks = 0; ks < 4; ++ks)
        afr[ks] = *(const short8*)(At + arow * 256 + ((ks * 64 + kgrp * 16) ^ ((arow & 7) << 4)));

    for (int cb = 0; cb < 6; ++cb) {
        const int nc0 = cb * 128;
        f32x4 acc[8];
        #pragma unroll
        for (int n = 0; n < 8; ++n) acc[n] = (f32x4){0,0,0,0};

        #pragma unroll
        for (int ks = 0; ks < 4; ++ks)
            #pragma unroll
            for (int n = 0; n < 8; ++n) {
                int colg = nc0 + n * 16 + lrow;
                short8 b = *(const short8*)&WiT[(size_t)colg * WDIM + ks * 32 + kgrp * 8];
                acc[n] = MFMA(afr[ks], b, acc[n]);
            }

        #pragma unroll
        for (int i = 0; i < 4; ++i) {
            float blo = bias[nc0 + 32 * i + lrow];
            float bhi = bias[nc0 + 32 * i + 16 + lrow];
            #pragma unroll
            for (int j = 0; j < 4; ++j) {
                size_t m = (size_t)(m0 + wid * 16 + kgrp * 4 + j);
                uint32_t pk = (uint32_t)f2bf(acc[2 * i][j] + blo)
                            | ((uint32_t)f2bf(acc[2 * i + 1][j] + bhi) << 16);
                *(uint32_t*)&EG[m * G3 + nc0 + 32 * i + 2 * lrow] = pk;
            }
        }
    }
}

// ============ recurrent kernel: h-part only, EG pair-gathered+prefetched ============
#define R_WHA 0          // Wh_a swizzled [256 cols][512B]  (128KB)
#define R_HBF 131072     // [16][512B] bf16 h, swizzled
#define R_RH  139264     // [16][512B] bf16 r*h, swizzled
#define R_TOK 147456     // [16][32] int tokens (2KB)
#define R_TOTAL 149504

extern __shared__ char smem[];

// GC/GN: 12 dwords; [g*4+j] holds pair (col ncol0+lrow | col ncol0+16+lrow) of gate g, row kgrp*4+j
#define GRU_STEP(T, GC, GN) do {                                              \
    int tn = ((T) + 1 < SEQ) ? (T) + 1 : SEQ - 1;                             \
    _Pragma("unroll")                                                         \
    for (int j = 0; j < 4; ++j) {                                             \
        int tok = tokL[(kgrp * 4 + j) * SEQ + tn];                            \
        const uint32_t* gp = EGd + (size_t)tok * 384 + gcoff;                 \
        GN[0 * 4 + j] = gp[0];                                                \
        GN[1 * 4 + j] = gp[128];                                              \
        GN[2 * 4 + j] = gp[256];                                              \
    }                                                                         \
    f32x4 az[2], ar[2];                                                       \
    _Pragma("unroll")                                                         \
    for (int j = 0; j < 4; ++j) {                                             \
        az[0][j] = bf2f_lo(GC[0 * 4 + j]);                                    \
        az[1][j] = bf2f_hi(GC[0 * 4 + j]);                                    \
        ar[0][j] = bf2f_lo(GC[1 * 4 + j]);                                    \
        ar[1][j] = bf2f_hi(GC[1 * 4 + j]);                                    \
    }                                                                         \
    _Pragma("unroll")                                                         \
    for (int ks = 0; ks < 8; ++ks) {                                          \
        short8 a = *(const short8*)(HBF + lrow * 512 + ((ks * 64 + kgrp * 16) ^ ((lrow & 7) << 4))); \
        az[0] = MFMA(a, Wz[ks][0], az[0]);                                    \
        az[1] = MFMA(a, Wz[ks][1], az[1]);                                    \
        ar[0] = MFMA(a, Wr[ks][0], ar[0]);                                    \
        ar[1] = MFMA(a, Wr[ks][1], ar[1]);                                    \
    }                                                                         \
    _Pragma("unroll")                                                         \
    for (int n = 0; n < 2; ++n) {                                             \
        int colg = ncol0 + n * 16 + lrow;                                     \
        _Pragma("unroll")                                                     \
        for (int j = 0; j < 4; ++j) {                                         \
            int row = kgrp * 4 + j;                                           \
            float zv = sigmoidf_(az[n][j]);                                   \
            az[n][j] = zv;                                                    \
            float rv = sigmoidf_(ar[n][j]);                                   \
            *(ushort*)(RH + row * 512 + ((colg * 2) ^ ((row & 7) << 4))) = f2bf(rv * h[n][j]); \
        }                                                                     \
    }                                                                         \
    __syncthreads();                                                          \
    f32x4 aa[2];                                                              \
    _Pragma("unroll")                                                         \
    for (int j = 0; j < 4; ++j) {                                             \
        aa[0][j] = bf2f_lo(GC[2 * 4 + j]);                                    \
        aa[1][j] = bf2f_hi(GC[2 * 4 + j]);                                    \
    }                                                                         \
    _Pragma("unroll")                                                         \
    for (int ks = 0; ks < 8; ++ks) {                                          \
        short8 a = *(const short8*)(RH + lrow * 512 + ((ks * 64 + kgrp * 16) ^ ((lrow & 7) << 4))); \
        _Pragma("unroll")                                                     \
        for (int n = 0; n < 2; ++n) {                                         \
            int colg = ncol0 + n * 16 + lrow;                                 \
            short8 bw = *(const short8*)(WhA + colg * 512 + ((ks * 64 + kgrp * 16) ^ ((colg & 7) << 4))); \
            aa[n] = MFMA(a, bw, aa[n]);                                       \
        }                                                                     \
    }                                                                         \
    _Pragma("unroll")                                                         \
    for (int n = 0; n < 2; ++n) {                                             \
        int colg = ncol0 + n * 16 + lrow;                                     \
        _Pragma("unroll")                                                     \
        for (int j = 0; j < 4; ++j) {                                         \
            int row = kgrp * 4 + j;                                           \
            float av = tanhf_(aa[n][j]);                                      \
            float zv = az[n][j];                                              \
            float hn = (1.f - zv) * h[n][j] + zv * av;                        \
            h[n][j] = hn;                                                     \
            *(ushort*)(HBF + row * 512 + ((colg * 2) ^ ((row & 7) << 4))) = f2bf(hn); \
        }                                                                     \
    }                                                                         \
    __syncthreads();                                                          \
} while (0)

__global__ __launch_bounds__(THREADS, 2) void gru_rec(
    const int* __restrict__ x, const ushort* __restrict__ EG,
    const float* __restrict__ bp, const ushort* __restrict__ WhT,
    const ushort* __restrict__ WpT, float* __restrict__ out)
{
    char* WhA = smem + R_WHA;
    char* HBF = smem + R_HBF;
    char* RH  = smem + R_RH;
    int*  tokL = (int*)(smem + R_TOK);

    const int tid  = threadIdx.x;
    const int lane = tid & 63;
    const int wid  = tid >> 6;
    const int lrow = lane & 15;
    const int kgrp = lane >> 4;
    const int r0   = blockIdx.x * BM;
    const int ncol0 = wid * 32;
    const uint32_t* EGd = (const uint32_t*)EG;
    const int gcoff = (ncol0 >> 1) + lrow;     // dword offset within EG row

    // one-time LDS fill: Wh_a swizzled
    for (int c = tid; c < 8192; c += THREADS) {
        int row = c >> 5, ch = c & 31;
        short8 v = *(const short8*)&WhT[(size_t)(2 * HID + row) * HID + ch * 8];
        *(short8*)(WhA + row * 512 + ((ch * 16) ^ ((row & 7) << 4))) = v;
    }
    *(short8*)(HBF + tid * 16) = (short8){0,0,0,0,0,0,0,0};
    tokL[tid] = x[r0 * SEQ + tid];       // 16 rows x 32 steps

    // resident Wh z/r fragments (128 VGPR), pinned against rematerialization
    short8 Wz[8][2], Wr[8][2];
    #pragma unroll
    for (int ks = 0; ks < 8; ++ks)
        #pragma unroll
        for (int n = 0; n < 2; ++n) {
            int colg = ncol0 + n * 16 + lrow;
            Wz[ks][n] = *(const short8*)&WhT[(size_t)colg * HID + ks * 32 + kgrp * 8];
            Wr[ks][n] = *(const short8*)&WhT[(size_t)(HID + colg) * HID + ks * 32 + kgrp * 8];
            asm volatile("" : "+v"(Wz[ks][n]), "+v"(Wr[ks][n]));
        }

    float bpr[2];
    #pragma unroll
    for (int n = 0; n < 2; ++n) bpr[n] = bp[ncol0 + n * 16 + lrow];

    float h[2][4] = {{0.f,0.f,0.f,0.f},{0.f,0.f,0.f,0.f}};

    __syncthreads();

    // prologue: gather EG pairs for t=0
    uint32_t gxA[12], gxB[12];
    #pragma unroll
    for (int j = 0; j < 4; ++j) {
        int tok = tokL[(kgrp * 4 + j) * SEQ + 0];
        const uint32_t* gp = EGd + (size_t)tok * 384 + gcoff;
        gxA[0 * 4 + j] = gp[0];
        gxA[1 * 4 + j] = gp[128];
        gxA[2 * 4 + j] = gp[256];
    }

    for (int t = 0; t < SEQ; t += 2) {
        GRU_STEP(t,     gxA, gxB);
        GRU_STEP(t + 1, gxB, gxA);
    }

    // ---- projection: out = h @ w_p + b_p ----
    f32x4 ap[2] = {{0,0,0,0},{0,0,0,0}};
    #pragma unroll
    for (int ks = 0; ks < 8; ++ks) {
        short8 a = *(const short8*)(HBF + lrow * 512 + ((ks * 64 + kgrp * 16) ^ ((lrow & 7) << 4)));
        #pragma unroll
        for (int n = 0; n < 2; ++n) {
            int colg = ncol0 + n * 16 + lrow;
            short8 bw = *(const short8*)&WpT[(size_t)colg * HID + ks * 32 + kgrp * 8];
            ap[n] = MFMA(a, bw, ap[n]);
        }
    }
    #pragma unroll
    for (int n = 0; n < 2; ++n) {
        int colg = ncol0 + n * 16 + lrow;
        #pragma unroll
        for (int j = 0; j < 4; ++j) {
            int row = kgrp * 4 + j;
            out[(size_t)(r0 + row) * HID + colg] = ap[n][j] + bpr[n];
        }
    }
}

// ============ fallback (known-good R2 kernel) if ws too small ============
#define F_WHA 0
#define F_XT  131072
#define F_HBF 139264
#define F_RH  147456
#define F_TOTAL 155648

__global__ __launch_bounds__(THREADS, 2) void gru_fallback(
    const int* __restrict__ x, const float* __restrict__ embed,
    const float* __restrict__ bias, const float* __restrict__ bp,
    const ushort* __restrict__ WiT, const ushort* __restrict__ WhT,
    const ushort* __restrict__ WpT, float* __restrict__ out)
{
    char* WhA = smem + F_WHA;
    char* XT  = smem + F_XT;
    char* HBF = smem + F_HBF;
    char* RH  = smem + F_RH;

    const int tid  = threadIdx.x;
    const int lane = tid & 63;
    const int wid  = tid >> 6;
    const int lrow = lane & 15;
    const int kgrp = lane >> 4;
    const int r0   = blockIdx.x * BM;
    const int ncol0 = wid * 32;
    const int grow = tid >> 5;
    const int gq   = tid & 31;

    for (int c = tid; c < 8192; c += THREADS) {
        int row = c >> 5, ch = c & 31;
        short8 v = *(const short8*)&WhT[(size_t)(2 * HID + row) * HID + ch * 8];
        *(short8*)(WhA + row * 512 + ((ch * 16) ^ ((row & 7) << 4))) = v;
    }
    *(short8*)(HBF + tid * 16) = (short8){0,0,0,0,0,0,0,0};
    {
        int tok = x[(r0 + grow) * SEQ + 0];
        float4 f = *(const float4*)&embed[(size_t)tok * WDIM + gq * 4];
        uint32_t p0 = f2bf(f.x) | ((uint32_t)f2bf(f.y) << 16);
        uint32_t p1 = f2bf(f.z) | ((uint32_t)f2bf(f.w) << 16);
        *(uint2*)(XT + grow * 256 + ((gq * 8) ^ ((grow & 7) << 4))) = (uint2){p0, p1};
    }

    short8 Wz[8][2], Wr[8][2];
    #pragma unroll
    for (int ks = 0; ks < 8; ++ks)
        #pragma unroll
        for (int n = 0; n < 2; ++n) {
            int colg = ncol0 + n * 16 + lrow;
            Wz[ks][n] = *(const short8*)&WhT[(size_t)colg * HID + ks * 32 + kgrp * 8];
            Wr[ks][n] = *(const short8*)&WhT[(size_t)(HID + colg) * HID + ks * 32 + kgrp * 8];
            asm volatile("" : "+v"(Wz[ks][n]), "+v"(Wr[ks][n]));
        }

    float bzr[2], brr[2], bar[2], bpr[2];
    #pragma unroll
    for (int n = 0; n < 2; ++n) {
        int colg = ncol0 + n * 16 + lrow;
        bzr[n] = bias[colg];
        brr[n] = bias[HID + colg];
        bar[n] = bias[2 * HID + colg];
        bpr[n] = bp[colg];
    }

    float h[2][4] = {{0.f,0.f,0.f,0.f},{0.f,0.f,0.f,0.f}};
    uint32_t zz = 0;

    __syncthreads();

    for (int t = 0; t < SEQ; ++t) {
        char* xt = XT + (t & 1) * 4096;
        char* xn = XT + ((t + 1) & 1) * 4096;

        asm volatile("" : "+v"(zz));
        const ushort* wiB = WiT + zz;

        int tp = (t + 1 < SEQ) ? t + 1 : SEQ - 1;
        int tok = x[(r0 + grow) * SEQ + tp];

        f32x4 az[2] = {{0,0,0,0},{0,0,0,0}};
        f32x4 ar[2] = {{0,0,0,0},{0,0,0,0}};

        #pragma unroll
        for (int ks = 0; ks < 4; ++ks) {
            short8 a = *(const short8*)(xt + lrow * 256 + ((ks * 64 + kgrp * 16) ^ ((lrow & 7) << 4)));
            #pragma unroll
            for (int n = 0; n < 2; ++n) {
                int colg = ncol0 + n * 16 + lrow;
                short8 bz = *(const short8*)&wiB[(size_t)colg * WDIM + ks * 32 + kgrp * 8];
                short8 br = *(const short8*)&wiB[(size_t)(HID + colg) * WDIM + ks * 32 + kgrp * 8];
                az[n] = MFMA(a, bz, az[n]);
                ar[n] = MFMA(a, br, ar[n]);
            }
        }
        #pragma unroll
        for (int ks = 0; ks < 8; ++ks) {
            short8 a = *(const short8*)(HBF + lrow * 512 + ((ks * 64 + kgrp * 16) ^ ((lrow & 7) << 4)));
            az[0] = MFMA(a, Wz[ks][0], az[0]);
            az[1] = MFMA(a, Wz[ks][1], az[1]);
            ar[0] = MFMA(a, Wr[ks][0], ar[0]);
            ar[1] = MFMA(a, Wr[ks][1], ar[1]);
        }

        float4 ef = *(const float4*)&embed[(size_t)tok * WDIM + gq * 4];

        #pragma unroll
        for (int n = 0; n < 2; ++n) {
            int colg = ncol0 + n * 16 + lrow;
            #pragma unroll
            for (int j = 0; j < 4; ++j) {
                int row = kgrp * 4 + j;
                float zv = sigmoidf_(az[n][j] + bzr[n]);
                az[n][j] = zv;
                float rv = sigmoidf_(ar[n][j] + brr[n]);
                *(ushort*)(RH + row * 512 + ((colg * 2) ^ ((row & 7) << 4))) = f2bf(rv * h[n][j]);
            }
        }
        __syncthreads();

        f32x4 aa[2] = {{0,0,0,0},{0,0,0,0}};
        #pragma unroll
        for (int ks = 0; ks < 4; ++ks) {
            short8 a = *(const short8*)(xt + lrow * 256 + ((ks * 64 + kgrp * 16) ^ ((lrow & 7) << 4)));
            #pragma unroll
            for (int n = 0; n < 2; ++n) {
                int colg = ncol0 + n * 16 + lrow;
                short8 bw = *(const short8*)&wiB[(size_t)(2 * HID + colg) * WDIM + ks * 32 + kgrp * 8];
                aa[n] = MFMA(a, bw, aa[n]);
            }
        }
        #pragma unroll
        for (int ks = 0; ks < 8; ++ks) {
            short8 a = *(const short8*)(RH + lrow * 512 + ((ks * 64 + kgrp * 16) ^ ((lrow & 7) << 4)));
            #pragma unroll
            for (int n = 0; n < 2; ++n) {
                int colg = ncol0 + n * 16 + lrow;
                short8 bw = *(const short8*)(WhA + colg * 512 + ((ks * 64 + kgrp * 16) ^ ((colg & 7) << 4)));
                aa[n] = MFMA(a, bw, aa[n]);
            }
        }

        #pragma unroll
        for (int n = 0; n < 2; ++n) {
            int colg = ncol0 + n * 16 + lrow;
            #pragma unroll
            for (int j = 0; j < 4; ++j) {
                int row = kgrp * 4 + j;
                float av = tanhf_(aa[n][j] + bar[n]);
                float zv = az[n][j];
                float hn = (1.f - zv) * h[n][j] + zv * av;
                h[n][j] = hn;
                *(ushort*)(HBF + row * 512 + ((colg * 2) ^ ((row & 7) << 4))) = f2bf(hn);
            }
        }

        {
            uint32_t p0 = f2bf(ef.x) | ((uint32_t)f2bf(ef.y) << 16);
            uint32_t p1 = f2bf(ef.z) | ((uint32_t)f2bf(ef.w) << 16);
            *(uint2*)(xn + grow * 256 + ((gq * 8) ^ ((grow & 7) << 4))) = (uint2){p0, p1};
        }
        __syncthreads();
    }

    f32x4 ap[2] = {{0,0,0,0},{0,0,0,0}};
    #pragma unroll
    for (int ks = 0; ks < 8; ++ks) {
        short8 a = *(const short8*)(HBF + lrow * 512 + ((ks * 64 + kgrp * 16) ^ ((lrow & 7) << 4)));
        #pragma unroll
        for (int n = 0; n < 2; ++n) {
            int colg = ncol0 + n * 16 + lrow;
            short8 bw = *(const short8*)&WpT[(size_t)colg * HID + ks * 32 + kgrp * 8];
            ap[n] = MFMA(a, bw, ap[n]);
        }
    }
    #pragma unroll
    for (int n = 0; n < 2; ++n) {
        int colg = ncol0 + n * 16 + lrow;
        #pragma unroll
        for (int j = 0; j < 4; ++j) {
            int row = kgrp * 4 + j;
            out[(size_t)(r0 + row) * HID + colg] = ap[n][j] + bpr[n];
        }
    }
}

extern "C" void kernel_launch(void* const* d_in, const int* in_sizes, int n_in,
                              void* d_out, int out_size, void* d_ws, size_t ws_size,
                              hipStream_t stream) {
    const int*   x     = (const int*)d_in[0];
    const float* embed = (const float*)d_in[1];
    const float* wi    = (const float*)d_in[2];
    const float* wh    = (const float*)d_in[3];
    const float* b     = (const float*)d_in[4];
    const float* wp    = (const float*)d_in[5];
    const float* bp    = (const float*)d_in[6];
    float* out = (float*)d_out;
    ushort* ws = (ushort*)d_ws;

    (void)hipFuncSetAttribute((const void*)gru_rec,
                              hipFuncAttributeMaxDynamicSharedMemorySize, R_TOTAL);
    (void)hipFuncSetAttribute((const void*)gru_fallback,
                              hipFuncAttributeMaxDynamicSharedMemorySize, F_TOTAL);

    hipLaunchKernelGGL(prep_kernel, dim3((WS_WTOTAL + 255) / 256), dim3(256), 0, stream,
                       wi, wh, wp, ws);

    if (ws_size >= WS_NEEDED) {
        ushort* eg = ws + WS_EG;
        hipLaunchKernelGGL(eg_kernel, dim3(EGROWS / EGM), dim3(256), 0, stream,
                           embed, b, ws + WS_WIT, eg);
        hipLaunchKernelGGL(gru_rec, dim3(BATCH / BM), dim3(THREADS), R_TOTAL, stream,
                           x, eg, bp, ws + WS_WHT, ws + WS_WPT, out);
    } else {
        hipLaunchKernelGGL(gru_fallback, dim3(BATCH / BM), dim3(THREADS), F_TOTAL, stream,
                           x, embed, b, bp, ws + WS_WIT, ws + WS_WHT, ws + WS_WPT, out);
    }
}

// Round 6
// 190.207 us; speedup vs baseline: 1.7673x; 1.1473x over previous
//
#include <hip/hip_runtime.h>
#include <stdint.h>

#define WDIM 128
#define HID 256
#define G3 768
#define VOCAB 50257
#define EGROWS 50304          // 786 * 64
#define BATCH 4096
#define SEQ 32
#define BM 16
#define THREADS 512

// ws layout (ushort units): WiT[768][128], WhT[768][256](K-permuted), WpT[256][256](K-permuted), EG[50304][768]
#define WS_WIT 0
#define WS_WHT 98304
#define WS_WPT 294912
#define WS_WTOTAL 360448
#define WS_EG  362496ULL      // byte offset 724992
#define WS_NEEDED (724992ULL + (unsigned long long)EGROWS * G3 * 2ULL)

typedef __attribute__((ext_vector_type(8))) short short8;
typedef __attribute__((ext_vector_type(4))) float f32x4;

#define MFMA(a, b, c) __builtin_amdgcn_mfma_f32_16x16x32_bf16((a), (b), (c), 0, 0, 0)

__device__ __forceinline__ ushort f2bf(float f) {
    union { float f; uint32_t u; } v; v.f = f;
    uint32_t u = v.u;
    u += 0x7fffu + ((u >> 16) & 1u);   // RNE
    return (ushort)(u >> 16);
}
__device__ __forceinline__ float bf2f_lo(uint32_t p) {
    union { uint32_t u; float f; } v; v.u = p << 16; return v.f;
}
__device__ __forceinline__ float bf2f_hi(uint32_t p) {
    union { uint32_t u; float f; } v; v.u = p & 0xffff0000u; return v.f;
}
__device__ __forceinline__ float sigmoidf_(float x) {
    return __builtin_amdgcn_rcpf(1.f + __expf(-x));
}
__device__ __forceinline__ float tanhf_(float x) {
    float e2 = __expf(2.f * x);
    return 1.f - 2.f * __builtin_amdgcn_rcpf(e2 + 1.f);
}
__device__ __forceinline__ uint32_t cvtpk_bf16(float lo, float hi) {
    uint32_t pk;
    asm("v_cvt_pk_bf16_f32 %0, %1, %2" : "=v"(pk) : "v"(lo), "v"(hi));
    return pk;
}
// K-slot permutation: slot s holds original k = col_of_slot(s); pairs (c, c+16) adjacent.
__device__ __forceinline__ int col_of_slot(int s) {
    return (s & ~31) | ((s & 31) >> 1) | ((s & 1) << 4);
}

__global__ void prep_kernel(const float* __restrict__ wi, const float* __restrict__ wh,
                            const float* __restrict__ wp, ushort* __restrict__ ws) {
    int gid = blockIdx.x * blockDim.x + threadIdx.x;
    if (gid < G3 * WDIM) {
        int n = gid / WDIM, k = gid % WDIM;
        ws[WS_WIT + n * WDIM + k] = f2bf(wi[k * G3 + n]);            // unpermuted (x-path)
    } else if (gid < G3 * WDIM + G3 * HID) {
        int g = gid - G3 * WDIM;
        int n = g / HID, s = g % HID;
        ws[WS_WHT + n * HID + s] = f2bf(wh[col_of_slot(s) * G3 + n]);  // K-permuted
    } else if (gid < G3 * WDIM + G3 * HID + HID * HID) {
        int g = gid - G3 * WDIM - G3 * HID;
        int n = g / HID, s = g % HID;
        ws[WS_WPT + n * HID + s] = f2bf(wp[col_of_slot(s) * HID + n]); // K-permuted
    }
}

// ============ EG = bf16( embed @ Wi + b ) : M=50304, N=768, K=128 ============
// Pair layout along G3: dword at ushort idx m*768 + nc0+32i+2*lrow = {col nc0+32i+lrow, col +16}.
// C routed through LDS transpose -> coalesced 64B short8 stores.
#define EGM 64

__global__ __launch_bounds__(256, 3) void eg_kernel(
    const float* __restrict__ embed, const float* __restrict__ bias,
    const ushort* __restrict__ WiT, ushort* __restrict__ EG)
{
    __shared__ char At[16384];            // [64 rows][256B] bf16, XOR-swizzled
    __shared__ char Tb[2][17408];         // [64 rows][272B] transpose buffers
    const int tid  = threadIdx.x;
    const int lane = tid & 63, wid = tid >> 6;
    const int lrow = lane & 15, kgrp = lane >> 4;
    const int m0  = blockIdx.x * EGM;

    {   // stage 64 embedding rows -> LDS bf16
        int row = tid >> 2, part = tid & 3;
        int er = m0 + row; if (er >= VOCAB) er = VOCAB - 1;
        const float* e = embed + (size_t)er * WDIM + part * 32;
        #pragma unroll
        for (int q = 0; q < 8; ++q) {
            float4 f = ((const float4*)e)[q];
            uint32_t p0 = f2bf(f.x) | ((uint32_t)f2bf(f.y) << 16);
            uint32_t p1 = f2bf(f.z) | ((uint32_t)f2bf(f.w) << 16);
            *(uint2*)(At + row * 256 + ((part * 64 + q * 8) ^ ((row & 7) << 4))) = (uint2){p0, p1};
        }
    }
    __syncthreads();

    const int arow = wid * 16 + lrow;
    short8 afr[4];
    #pragma unroll
    for (int ks = 0; ks < 4; ++ks)
        afr[ks] = *(const short8*)(At + arow * 256 + ((ks * 64 + kgrp * 16) ^ ((arow & 7) << 4)));

    const int srow = tid >> 2, sub = tid & 3;

    for (int cb = 0; cb < 6; ++cb) {
        const int nc0 = cb * 128;
        f32x4 acc[8];
        #pragma unroll
        for (int n = 0; n < 8; ++n) acc[n] = (f32x4){0,0,0,0};

        #pragma unroll
        for (int ks = 0; ks < 4; ++ks)
            #pragma unroll
            for (int n = 0; n < 8; ++n) {
                int colg = nc0 + n * 16 + lrow;
                short8 b = *(const short8*)&WiT[(size_t)colg * WDIM + ks * 32 + kgrp * 8];
                acc[n] = MFMA(afr[ks], b, acc[n]);
            }

        char* T = Tb[cb & 1];
        #pragma unroll
        for (int i = 0; i < 4; ++i) {
            float blo = bias[nc0 + 32 * i + lrow];
            float bhi = bias[nc0 + 32 * i + 16 + lrow];
            #pragma unroll
            for (int j = 0; j < 4; ++j) {
                int row = wid * 16 + kgrp * 4 + j;
                uint32_t pk = cvtpk_bf16(acc[2 * i][j] + blo, acc[2 * i + 1][j] + bhi);
                *(uint32_t*)(T + row * 272 + i * 64 + lrow * 4) = pk;
            }
        }
        __syncthreads();

        #pragma unroll
        for (int q = 0; q < 4; ++q) {
            short8 v = *(const short8*)(T + srow * 272 + q * 64 + sub * 16);
            *(short8*)((char*)EG + (size_t)(m0 + srow) * 1536 + cb * 256 + q * 64 + sub * 16) = v;
        }
    }
}

// ============ recurrent kernel: h-part only, EG pair-gathered+prefetched ============
#define R_WHA 0          // Wh_a (K-permuted rows) swizzled [256 cols][512B]  (128KB)
#define R_HBF 131072     // [16][512B] bf16 h, pair-slot layout, swizzled
#define R_RH  139264     // [16][512B] bf16 r*h, pair-slot layout, swizzled
#define R_TOK 147456     // [16][32] int tokens (2KB)
#define R_TOTAL 149504

extern __shared__ char smem[];

// raw barrier: flush LDS writes only; VMEM (EG prefetch) stays in flight
#define RAW_BARRIER() do {                                                    \
    asm volatile("s_waitcnt lgkmcnt(0)" ::: "memory");                        \
    __builtin_amdgcn_s_barrier();                                             \
    __builtin_amdgcn_sched_barrier(0);                                        \
} while (0)

// GC/GN: 12 dwords; [g*4+j] = pair (col ncol0+lrow | col ncol0+16+lrow) of gate g, row kgrp*4+j
#define GRU_STEP(T, GC, GN) do {                                              \
    int tn = ((T) + 1 < SEQ) ? (T) + 1 : SEQ - 1;                             \
    _Pragma("unroll")                                                         \
    for (int j = 0; j < 4; ++j) {                                             \
        int tok = tokL[(kgrp * 4 + j) * SEQ + tn];                            \
        const uint32_t* gp = EGd + (size_t)tok * 384 + gcoff;                 \
        GN[0 * 4 + j] = gp[0];                                                \
        GN[1 * 4 + j] = gp[128];                                              \
        GN[2 * 4 + j] = gp[256];                                              \
    }                                                                         \
    f32x4 az[2], ar[2];                                                       \
    _Pragma("unroll")                                                         \
    for (int j = 0; j < 4; ++j) {                                             \
        az[0][j] = bf2f_lo(GC[0 * 4 + j]);                                    \
        az[1][j] = bf2f_hi(GC[0 * 4 + j]);                                    \
        ar[0][j] = bf2f_lo(GC[1 * 4 + j]);                                    \
        ar[1][j] = bf2f_hi(GC[1 * 4 + j]);                                    \
    }                                                                         \
    _Pragma("unroll")                                                         \
    for (int ks = 0; ks < 8; ++ks) {                                          \
        short8 a = *(const short8*)(HBF + lrow * 512 + ((ks * 64 + kgrp * 16) ^ ((lrow & 7) << 4))); \
        az[0] = MFMA(a, Wz[ks][0], az[0]);                                    \
        az[1] = MFMA(a, Wz[ks][1], az[1]);                                    \
        ar[0] = MFMA(a, Wr[ks][0], ar[0]);                                    \
        ar[1] = MFMA(a, Wr[ks][1], ar[1]);                                    \
    }                                                                         \
    _Pragma("unroll")                                                         \
    for (int j = 0; j < 4; ++j) {                                             \
        int row = kgrp * 4 + j;                                               \
        float z0 = sigmoidf_(az[0][j]); az[0][j] = z0;                        \
        float z1 = sigmoidf_(az[1][j]); az[1][j] = z1;                        \
        float r0 = sigmoidf_(ar[0][j]) * h[0][j];                             \
        float r1 = sigmoidf_(ar[1][j]) * h[1][j];                             \
        *(uint32_t*)(RH + row * 512 + ((wid * 64 + lrow * 4) ^ ((row & 7) << 4))) = cvtpk_bf16(r0, r1); \
    }                                                                         \
    RAW_BARRIER();                                                            \
    f32x4 aa[2];                                                              \
    _Pragma("unroll")                                                         \
    for (int j = 0; j < 4; ++j) {                                             \
        aa[0][j] = bf2f_lo(GC[2 * 4 + j]);                                    \
        aa[1][j] = bf2f_hi(GC[2 * 4 + j]);                                    \
    }                                                                         \
    _Pragma("unroll")                                                         \
    for (int ks = 0; ks < 8; ++ks) {                                          \
        short8 a = *(const short8*)(RH + lrow * 512 + ((ks * 64 + kgrp * 16) ^ ((lrow & 7) << 4))); \
        _Pragma("unroll")                                                     \
        for (int n = 0; n < 2; ++n) {                                         \
            int colg = ncol0 + n * 16 + lrow;                                 \
            short8 bw = *(const short8*)(WhA + colg * 512 + ((ks * 64 + kgrp * 16) ^ ((colg & 7) << 4))); \
            aa[n] = MFMA(a, bw, aa[n]);                                       \
        }                                                                     \
    }                                                                         \
    _Pragma("unroll")                                                         \
    for (int j = 0; j < 4; ++j) {                                             \
        int row = kgrp * 4 + j;                                               \
        float a0 = tanhf_(aa[0][j]);                                          \
        float a1 = tanhf_(aa[1][j]);                                          \
        float h0 = (1.f - az[0][j]) * h[0][j] + az[0][j] * a0;                \
        float h1 = (1.f - az[1][j]) * h[1][j] + az[1][j] * a1;                \
        h[0][j] = h0; h[1][j] = h1;                                           \
        *(uint32_t*)(HBF + row * 512 + ((wid * 64 + lrow * 4) ^ ((row & 7) << 4))) = cvtpk_bf16(h0, h1); \
    }                                                                         \
    RAW_BARRIER();                                                            \
} while (0)

__global__ __launch_bounds__(THREADS, 2) void gru_rec(
    const int* __restrict__ x, const ushort* __restrict__ EG,
    const float* __restrict__ bp, const ushort* __restrict__ WhT,
    const ushort* __restrict__ WpT, float* __restrict__ out)
{
    char* WhA = smem + R_WHA;
    char* HBF = smem + R_HBF;
    char* RH  = smem + R_RH;
    int*  tokL = (int*)(smem + R_TOK);

    const int tid  = threadIdx.x;
    const int lane = tid & 63;
    const int wid  = tid >> 6;
    const int lrow = lane & 15;
    const int kgrp = lane >> 4;
    const int r0   = blockIdx.x * BM;
    const int ncol0 = wid * 32;
    const uint32_t* EGd = (const uint32_t*)EG;
    const int gcoff = (ncol0 >> 1) + lrow;     // dword offset within EG row

    // one-time LDS fill: Wh_a (rows are K-permuted already), swizzled
    for (int c = tid; c < 8192; c += THREADS) {
        int row = c >> 5, ch = c & 31;
        short8 v = *(const short8*)&WhT[(size_t)(2 * HID + row) * HID + ch * 8];
        *(short8*)(WhA + row * 512 + ((ch * 16) ^ ((row & 7) << 4))) = v;
    }
    *(short8*)(HBF + tid * 16) = (short8){0,0,0,0,0,0,0,0};
    tokL[tid] = x[r0 * SEQ + tid];       // 16 rows x 32 steps

    // resident Wh z/r fragments (K-permuted), pinned against rematerialization
    short8 Wz[8][2], Wr[8][2];
    #pragma unroll
    for (int ks = 0; ks < 8; ++ks)
        #pragma unroll
        for (int n = 0; n < 2; ++n) {
            int colg = ncol0 + n * 16 + lrow;
            Wz[ks][n] = *(const short8*)&WhT[(size_t)colg * HID + ks * 32 + kgrp * 8];
            Wr[ks][n] = *(const short8*)&WhT[(size_t)(HID + colg) * HID + ks * 32 + kgrp * 8];
            asm volatile("" : "+v"(Wz[ks][n]), "+v"(Wr[ks][n]));
        }

    float bpr[2];
    #pragma unroll
    for (int n = 0; n < 2; ++n) bpr[n] = bp[ncol0 + n * 16 + lrow];

    float h[2][4] = {{0.f,0.f,0.f,0.f},{0.f,0.f,0.f,0.f}};

    __syncthreads();

    // prologue: gather EG pairs for t=0
    uint32_t gxA[12], gxB[12];
    #pragma unroll
    for (int j = 0; j < 4; ++j) {
        int tok = tokL[(kgrp * 4 + j) * SEQ + 0];
        const uint32_t* gp = EGd + (size_t)tok * 384 + gcoff;
        gxA[0 * 4 + j] = gp[0];
        gxA[1 * 4 + j] = gp[128];
        gxA[2 * 4 + j] = gp[256];
    }

    for (int t = 0; t < SEQ; t += 2) {
        GRU_STEP(t,     gxA, gxB);
        GRU_STEP(t + 1, gxB, gxA);
    }

    // ---- projection: out = h @ w_p + b_p (WpT K-permuted to match HBF slots) ----
    f32x4 ap[2] = {{0,0,0,0},{0,0,0,0}};
    #pragma unroll
    for (int ks = 0; ks < 8; ++ks) {
        short8 a = *(const short8*)(HBF + lrow * 512 + ((ks * 64 + kgrp * 16) ^ ((lrow & 7) << 4)));
        #pragma unroll
        for (int n = 0; n < 2; ++n) {
            int colg = ncol0 + n * 16 + lrow;
            short8 bw = *(const short8*)&WpT[(size_t)colg * HID + ks * 32 + kgrp * 8];
            ap[n] = MFMA(a, bw, ap[n]);
        }
    }
    #pragma unroll
    for (int n = 0; n < 2; ++n) {
        int colg = ncol0 + n * 16 + lrow;
        #pragma unroll
        for (int j = 0; j < 4; ++j) {
            int row = kgrp * 4 + j;
            out[(size_t)(r0 + row) * HID + colg] = ap[n][j] + bpr[n];
        }
    }
}

extern "C" void kernel_launch(void* const* d_in, const int* in_sizes, int n_in,
                              void* d_out, int out_size, void* d_ws, size_t ws_size,
                              hipStream_t stream) {
    const int*   x     = (const int*)d_in[0];
    const float* embed = (const float*)d_in[1];
    const float* wi    = (const float*)d_in[2];
    const float* wh    = (const float*)d_in[3];
    const float* b     = (const float*)d_in[4];
    const float* wp    = (const float*)d_in[5];
    const float* bp    = (const float*)d_in[6];
    float* out = (float*)d_out;
    ushort* ws = (ushort*)d_ws;

    (void)hipFuncSetAttribute((const void*)gru_rec,
                              hipFuncAttributeMaxDynamicSharedMemorySize, R_TOTAL);

    hipLaunchKernelGGL(prep_kernel, dim3((WS_WTOTAL + 255) / 256), dim3(256), 0, stream,
                       wi, wh, wp, ws);

    ushort* eg = ws + WS_EG;
    hipLaunchKernelGGL(eg_kernel, dim3(EGROWS / EGM), dim3(256), 0, stream,
                       embed, b, ws + WS_WIT, eg);
    hipLaunchKernelGGL(gru_rec, dim3(BATCH / BM), dim3(THREADS), R_TOTAL, stream,
                       x, eg, bp, ws + WS_WHT, ws + WS_WPT, out);
}